// Round 17
// baseline (197.630 us; speedup 1.0000x reference)
//
#include <hip/hip_runtime.h>
#include <hip/hip_bf16.h>
#include <cstdint>

#define CH 2048
#define NCF 8192          // 4 * CH
#define NJ 24             // 4 pre + 4 post + 16 res
#define RPB 4             // batch rows per block
#define EPS_F 1e-5f
#define SINK_ITERS 20

typedef float v4f __attribute__((ext_vector_type(4)));

__device__ __forceinline__ int dot4i8(uint32_t a, uint32_t b, int c) {
#if __has_builtin(__builtin_amdgcn_sdot4)
    return __builtin_amdgcn_sdot4((int)a, (int)b, c, false);
#else
    int d;
    asm("v_dot4_i32_i8 %0, %1, %2, %3" : "=v"(d) : "v"(a), "v"(b), "v"(c));
    return d;
#endif
}

// ---------------------------------------------------------------------------
// Prep pass 1: per-row absmax of weighted phi -> amaxphi[24]
// ---------------------------------------------------------------------------
__global__ void __launch_bounds__(256) prep_amax_kernel(
    const float* __restrict__ w,
    const float* __restrict__ phi_pre,
    const float* __restrict__ phi_post,
    const float* __restrict__ phi_res,
    const float* __restrict__ alpha_pre,
    const float* __restrict__ alpha_post,
    const float* __restrict__ alpha_res,
    float* __restrict__ amaxphi)
{
    const int j = blockIdx.x;          // 0..23
    const int t = threadIdx.x;
    const float* src; float a;
    if (j < 4)      { src = phi_pre  + (size_t)j * NCF;       a = alpha_pre[0]; }
    else if (j < 8) { src = phi_post + (size_t)(j-4) * NCF;   a = alpha_post[0]; }
    else            { src = phi_res  + (size_t)(j-8) * NCF;   a = alpha_res[0]; }
    float m = 0.f;
    for (int k = t; k < NCF; k += 256)
        m = fmaxf(m, fabsf(src[k] * a * w[k & (CH - 1)]));
    #pragma unroll
    for (int s = 1; s < 64; s <<= 1) m = fmaxf(m, __shfl_xor(m, s, 64));
    __shared__ float wm[4];
    if ((t & 63) == 0) wm[t >> 6] = m;
    __syncthreads();
    if (t == 0)
        amaxphi[j] = fmaxf(fmaxf(fmaxf(wm[0], wm[1]), fmaxf(wm[2], wm[3])), 1e-30f);
}

// ---------------------------------------------------------------------------
// Prep pass 2: qphi[j][k] = int8( round( w*alpha*phi * 127/amaxphi[j] ) )
// ---------------------------------------------------------------------------
__global__ void __launch_bounds__(256) prep_quant_kernel(
    const float* __restrict__ w,
    const float* __restrict__ phi_pre,
    const float* __restrict__ phi_post,
    const float* __restrict__ phi_res,
    const float* __restrict__ alpha_pre,
    const float* __restrict__ alpha_post,
    const float* __restrict__ alpha_res,
    const float* __restrict__ amaxphi,
    int8_t* __restrict__ qphi)
{
    int idx = blockIdx.x * 256 + threadIdx.x;
    if (idx >= NJ * NCF) return;
    int j = idx / NCF;
    int k = idx - j * NCF;
    int c = k & (CH - 1);
    float v, a;
    if (j < 4)      { v = phi_pre[j * NCF + k];        a = alpha_pre[0]; }
    else if (j < 8) { v = phi_post[(j - 4) * NCF + k]; a = alpha_post[0]; }
    else            { v = phi_res[(j - 8) * NCF + k];  a = alpha_res[0]; }
    float f = v * a * w[c] * (127.0f / amaxphi[j]);
    f = fminf(fmaxf(f, -127.0f), 127.0f);
    qphi[idx] = (int8_t)(int)__builtin_rintf(f);
}

// ---------------------------------------------------------------------------
// Main fused kernel: 512 threads (8 waves), FOUR batch rows per block.
// x quantized to int8 per-(row,stream) absmax -> LDS 32 KiB -> 4 blocks/CU.
// Phase A: pass1 reduce (sumsq + absmax) -> barrier -> pass2 quantize (x
// re-read from hot L2). Phase B: v_dot4_i32_i8, scl*dequant folded at
// stream-segment boundaries; scales recomputed from LDS (no persistent
// regs). Sinkhorn redundant on all waves; epilogue M-fold absorbs dequant.
// ---------------------------------------------------------------------------
__global__ void __launch_bounds__(512) mhc_main_kernel(
    const float* __restrict__ x,
    const int8_t* __restrict__ qphi,
    const float* __restrict__ amaxphi,
    const float* __restrict__ b_pre,
    const float* __restrict__ b_post,
    const float* __restrict__ b_res,
    float* __restrict__ out)
{
    const int t = threadIdx.x;
    const int lane = t & 63;
    const int wave = t >> 6;              // 0..7
    const long b0 = (long)blockIdx.x * RPB;

    __shared__ uint32_t xn8[RPB][NCF / 4];    // int8 x, 32 KiB
    __shared__ float4 redSS[RPB][8];          // sum-of-squares partials
    __shared__ float4 redAM[RPB][8];          // absmax partials
    __shared__ float H[RPB][24] __attribute__((aligned(16)));
    __shared__ float MS[RPB][16] __attribute__((aligned(16)));

    const float4* xp = reinterpret_cast<const float4*>(x + b0 * NCF);

    // ---- Phase A pass 1: sumsq + absmax per (row, stream) ----
    #pragma unroll
    for (int r = 0; r < RPB; ++r) {
        float4 a0 = xp[r * 2048 + t];
        float4 a1 = xp[r * 2048 + t + 512];
        float4 a2 = xp[r * 2048 + t + 1024];
        float4 a3 = xp[r * 2048 + t + 1536];
        float ss0 = a0.x*a0.x + a0.y*a0.y + a0.z*a0.z + a0.w*a0.w;
        float ss1 = a1.x*a1.x + a1.y*a1.y + a1.z*a1.z + a1.w*a1.w;
        float ss2 = a2.x*a2.x + a2.y*a2.y + a2.z*a2.z + a2.w*a2.w;
        float ss3 = a3.x*a3.x + a3.y*a3.y + a3.z*a3.z + a3.w*a3.w;
        float m0 = fmaxf(fmaxf(fabsf(a0.x), fabsf(a0.y)), fmaxf(fabsf(a0.z), fabsf(a0.w)));
        float m1 = fmaxf(fmaxf(fabsf(a1.x), fabsf(a1.y)), fmaxf(fabsf(a1.z), fabsf(a1.w)));
        float m2 = fmaxf(fmaxf(fabsf(a2.x), fabsf(a2.y)), fmaxf(fabsf(a2.z), fabsf(a2.w)));
        float m3 = fmaxf(fmaxf(fabsf(a3.x), fabsf(a3.y)), fmaxf(fabsf(a3.z), fabsf(a3.w)));
        #pragma unroll
        for (int s = 1; s < 64; s <<= 1) {
            ss0 += __shfl_xor(ss0, s, 64); ss1 += __shfl_xor(ss1, s, 64);
            ss2 += __shfl_xor(ss2, s, 64); ss3 += __shfl_xor(ss3, s, 64);
            m0 = fmaxf(m0, __shfl_xor(m0, s, 64));
            m1 = fmaxf(m1, __shfl_xor(m1, s, 64));
            m2 = fmaxf(m2, __shfl_xor(m2, s, 64));
            m3 = fmaxf(m3, __shfl_xor(m3, s, 64));
        }
        if (lane == 0) {
            redSS[r][wave] = make_float4(ss0, ss1, ss2, ss3);
            redAM[r][wave] = make_float4(m0, m1, m2, m3);
        }
    }
    __syncthreads();

    // ---- Phase A pass 2: quantize (x re-read from hot L2) ----
    #pragma unroll
    for (int r = 0; r < RPB; ++r) {
        float qs[4];
        #pragma unroll
        for (int s = 0; s < 4; ++s) {
            float am = 1e-30f;
            #pragma unroll
            for (int w8 = 0; w8 < 8; ++w8)
                am = fmaxf(am, ((const float*)&redAM[r][w8])[s]);
            qs[s] = 127.0f / am;
        }
        #pragma unroll
        for (int jj = 0; jj < 4; ++jj) {
            float4 v = xp[r * 2048 + t + 512 * jj];
            const float q = qs[jj];
            int q0 = (int)__builtin_rintf(fminf(fmaxf(v.x * q, -127.f), 127.f));
            int q1 = (int)__builtin_rintf(fminf(fmaxf(v.y * q, -127.f), 127.f));
            int q2 = (int)__builtin_rintf(fminf(fmaxf(v.z * q, -127.f), 127.f));
            int q3 = (int)__builtin_rintf(fminf(fmaxf(v.w * q, -127.f), 127.f));
            xn8[r][t + 512 * jj] = (uint32_t)(q0 & 255) | ((uint32_t)(q1 & 255) << 8)
                                 | ((uint32_t)(q2 & 255) << 16) | ((uint32_t)(q3 & 255) << 24);
        }
    }
    __syncthreads();

    // ---- Phase B: wave w dots 4 rows vs phi rows 3w..3w+2 (int8 dot4) ----
    float accT[3][RPB] = {};
    int   accS[3][RPB] = {};
    {
        const int8_t* pw = qphi + (size_t)(wave * 3) * NCF;
        float aphi[3];
        #pragma unroll
        for (int jl = 0; jl < 3; ++jl)
            aphi[jl] = amaxphi[3 * wave + jl] * (1.0f / 127.0f);
        const int kl = 8 * lane;
        const uint2* xw0 = reinterpret_cast<const uint2*>(xn8[0]);
        const uint2* xw1 = reinterpret_cast<const uint2*>(xn8[1]);
        const uint2* xw2 = reinterpret_cast<const uint2*>(xn8[2]);
        const uint2* xw3 = reinterpret_cast<const uint2*>(xn8[3]);

        uint2 pA0 = *reinterpret_cast<const uint2*>(pw + 0 * NCF + kl);
        uint2 pA1 = *reinterpret_cast<const uint2*>(pw + 1 * NCF + kl);
        uint2 pA2 = *reinterpret_cast<const uint2*>(pw + 2 * NCF + kl);

        #pragma unroll
        for (int u = 0; u < 16; ++u) {
            uint2 pN0, pN1, pN2;
            if (u + 1 < 16) {                     // prefetch next phi step
                const int kN = 512 * (u + 1) + kl;
                pN0 = *reinterpret_cast<const uint2*>(pw + 0 * NCF + kN);
                pN1 = *reinterpret_cast<const uint2*>(pw + 1 * NCF + kN);
                pN2 = *reinterpret_cast<const uint2*>(pw + 2 * NCF + kN);
            }
            const int xi = 64 * u + lane;
            uint2 x0 = xw0[xi], x1 = xw1[xi], x2 = xw2[xi], x3 = xw3[xi];

            accS[0][0] = dot4i8(x0.y, pA0.y, dot4i8(x0.x, pA0.x, accS[0][0]));
            accS[0][1] = dot4i8(x1.y, pA0.y, dot4i8(x1.x, pA0.x, accS[0][1]));
            accS[0][2] = dot4i8(x2.y, pA0.y, dot4i8(x2.x, pA0.x, accS[0][2]));
            accS[0][3] = dot4i8(x3.y, pA0.y, dot4i8(x3.x, pA0.x, accS[0][3]));
            accS[1][0] = dot4i8(x0.y, pA1.y, dot4i8(x0.x, pA1.x, accS[1][0]));
            accS[1][1] = dot4i8(x1.y, pA1.y, dot4i8(x1.x, pA1.x, accS[1][1]));
            accS[1][2] = dot4i8(x2.y, pA1.y, dot4i8(x2.x, pA1.x, accS[1][2]));
            accS[1][3] = dot4i8(x3.y, pA1.y, dot4i8(x3.x, pA1.x, accS[1][3]));
            accS[2][0] = dot4i8(x0.y, pA2.y, dot4i8(x0.x, pA2.x, accS[2][0]));
            accS[2][1] = dot4i8(x1.y, pA2.y, dot4i8(x1.x, pA2.x, accS[2][1]));
            accS[2][2] = dot4i8(x2.y, pA2.y, dot4i8(x2.x, pA2.x, accS[2][2]));
            accS[2][3] = dot4i8(x3.y, pA2.y, dot4i8(x3.x, pA2.x, accS[2][3]));

            if ((u & 3) == 3) {                   // stream-segment boundary
                const int s = u >> 2;
                float cx[RPB];
                #pragma unroll
                for (int r = 0; r < RPB; ++r) {
                    float ss = 0.f, am = 1e-30f;
                    #pragma unroll
                    for (int w8 = 0; w8 < 8; ++w8) {
                        ss += ((const float*)&redSS[r][w8])[s];
                        am = fmaxf(am, ((const float*)&redAM[r][w8])[s]);
                    }
                    cx[r] = rsqrtf(ss * (1.0f / CH) + EPS_F) * (am * (1.0f / 127.0f));
                }
                #pragma unroll
                for (int jl = 0; jl < 3; ++jl)
                    #pragma unroll
                    for (int r = 0; r < RPB; ++r) {
                        accT[jl][r] = fmaf(cx[r] * aphi[jl], (float)accS[jl][r], accT[jl][r]);
                        accS[jl][r] = 0;
                    }
            }
            pA0 = pN0; pA1 = pN1; pA2 = pN2;
        }
    }
    {
        #pragma unroll
        for (int s = 1; s < 64; s <<= 1) {
            #pragma unroll
            for (int jl = 0; jl < 3; ++jl)
                #pragma unroll
                for (int r = 0; r < RPB; ++r)
                    accT[jl][r] += __shfl_xor(accT[jl][r], s, 64);
        }
        if (lane == 0) {
            #pragma unroll
            for (int jl = 0; jl < 3; ++jl) {
                int j = 3 * wave + jl;
                float bias;
                if (j < 4)      bias = b_pre[j];
                else if (j < 8) bias = b_post[j - 4];
                else            bias = b_res[j - 8];
                #pragma unroll
                for (int r = 0; r < RPB; ++r) H[r][j] = accT[jl][r] + bias;
            }
        }
    }
    __syncthreads();

    // ---- Sinkhorn: every wave computes all 4 rows redundantly ----
    {
        const int r = lane >> 4;
        const int q = lane & 15;          // q = i*4 + jx
        float L = H[r][8 + q];
        float mx = L;
        mx = fmaxf(mx, __shfl_xor(mx, 1, 64));
        mx = fmaxf(mx, __shfl_xor(mx, 2, 64));
        mx = fmaxf(mx, __shfl_xor(mx, 4, 64));
        mx = fmaxf(mx, __shfl_xor(mx, 8, 64));
        float m = __expf(L - mx);
        #pragma unroll
        for (int it = 0; it < SINK_ITERS; ++it) {
            float rs = m + __shfl_xor(m, 1, 64);
            rs += __shfl_xor(rs, 2, 64);
            m = m * __builtin_amdgcn_rcpf(rs + EPS_F);   // row normalize
            float cs = m + __shfl_xor(m, 4, 64);
            cs += __shfl_xor(cs, 8, 64);
            m = m * __builtin_amdgcn_rcpf(cs + EPS_F);   // col normalize
        }
        MS[r][q] = m;
    }

    // ---- Phase D: out[i,c] = sum_j M'[i,j]*xi8[j,c],
    //      M' = (hrm + hq (x) hp) * dq_stream  (dequant folded into M) ----
    #pragma unroll
    for (int r = 0; r < RPB; ++r) {
        const float4 hp = *reinterpret_cast<const float4*>(&H[r][0]);
        const float4 hq = *reinterpret_cast<const float4*>(&H[r][4]);
        float dq[4];
        #pragma unroll
        for (int s = 0; s < 4; ++s) {
            float am = 1e-30f;
            #pragma unroll
            for (int w8 = 0; w8 < 8; ++w8)
                am = fmaxf(am, ((const float*)&redAM[r][w8])[s]);
            dq[s] = am * (1.0f / 127.0f);
        }
        float4 M[4];
        #pragma unroll
        for (int i = 0; i < 4; ++i) {
            float4 hrm = *reinterpret_cast<const float4*>(&MS[r][4 * i]);
            const float qv = (i == 0) ? hq.x : (i == 1) ? hq.y : (i == 2) ? hq.z : hq.w;
            M[i].x = fmaf(qv, hp.x, hrm.x) * dq[0];
            M[i].y = fmaf(qv, hp.y, hrm.y) * dq[1];
            M[i].z = fmaf(qv, hp.z, hrm.z) * dq[2];
            M[i].w = fmaf(qv, hp.w, hrm.w) * dq[3];
        }
        float4 s[4];
        #pragma unroll
        for (int jj = 0; jj < 4; ++jj) {
            uint32_t pk = xn8[r][t + 512 * jj];
            s[jj].x = (float)((int)(pk << 24) >> 24);
            s[jj].y = (float)((int)(pk << 16) >> 24);
            s[jj].z = (float)((int)(pk << 8) >> 24);
            s[jj].w = (float)((int)pk >> 24);
        }
        v4f* op = reinterpret_cast<v4f*>(out + (b0 + r) * NCF + 4 * t);
        #pragma unroll
        for (int i = 0; i < 4; ++i) {
            v4f o;
            o.x = M[i].x*s[0].x + M[i].y*s[1].x + M[i].z*s[2].x + M[i].w*s[3].x;
            o.y = M[i].x*s[0].y + M[i].y*s[1].y + M[i].z*s[2].y + M[i].w*s[3].y;
            o.z = M[i].x*s[0].z + M[i].y*s[1].z + M[i].z*s[2].z + M[i].w*s[3].z;
            o.w = M[i].x*s[0].w + M[i].y*s[1].w + M[i].z*s[2].w + M[i].w*s[3].w;
            __builtin_nontemporal_store(o, op + i * 512);
        }
    }
}

extern "C" void kernel_launch(void* const* d_in, const int* in_sizes, int n_in,
                              void* d_out, int out_size, void* d_ws, size_t ws_size,
                              hipStream_t stream)
{
    const float* x        = (const float*)d_in[0];
    const float* w        = (const float*)d_in[1];
    const float* phi_pre  = (const float*)d_in[2];
    const float* phi_post = (const float*)d_in[3];
    const float* phi_res  = (const float*)d_in[4];
    const float* b_pre    = (const float*)d_in[5];
    const float* b_post   = (const float*)d_in[6];
    const float* b_res    = (const float*)d_in[7];
    const float* a_pre    = (const float*)d_in[8];
    const float* a_post   = (const float*)d_in[9];
    const float* a_res    = (const float*)d_in[10];
    float* out = (float*)d_out;

    int8_t* qphi   = (int8_t*)d_ws;                              // 192 KiB
    float* amaxphi = (float*)((char*)d_ws + (size_t)NJ * NCF);   // 96 B

    const int B = in_sizes[0] / NCF;    // 8192

    prep_amax_kernel<<<NJ, 256, 0, stream>>>(
        w, phi_pre, phi_post, phi_res, a_pre, a_post, a_res, amaxphi);

    prep_quant_kernel<<<(NJ * NCF + 255) / 256, 256, 0, stream>>>(
        w, phi_pre, phi_post, phi_res, a_pre, a_post, a_res, amaxphi, qphi);

    mhc_main_kernel<<<B / RPB, 512, 0, stream>>>(
        x, qphi, amaxphi, b_pre, b_post, b_res, out);
}

// Round 18
// 189.153 us; speedup vs baseline: 1.0448x; 1.0448x over previous
//
#include <hip/hip_runtime.h>
#include <hip/hip_bf16.h>
#include <cstdint>

#define CH 2048
#define NCF 8192          // 4 * CH
#define NJ 24             // 4 pre + 4 post + 16 res
#define EPS_F 1e-5f
#define SINK_ITERS 20

typedef float v4f __attribute__((ext_vector_type(4)));

__device__ __forceinline__ uint32_t bf16rne(float f) {
    uint32_t u = __float_as_uint(f);
    return (u + 0x7fffu + ((u >> 16) & 1u)) >> 16;
}

// pack 2 f32 -> 2 bf16 in one instruction (lo -> [15:0], hi -> [31:16])
__device__ __forceinline__ uint32_t cvtpk(float lo, float hi) {
    uint32_t r;
    asm("v_cvt_pk_bf16_f32 %0, %1, %2" : "=v"(r) : "v"(lo), "v"(hi));
    return r;
}

// dot of 8 bf16 pairs (packed in uint4) via v_dot2_f32_bf16
__device__ __forceinline__ float dot8(const uint4& x, const uint4& p, float acc) {
    asm("v_dot2_f32_bf16 %0, %1, %2, %0" : "+v"(acc) : "v"(x.x), "v"(p.x));
    asm("v_dot2_f32_bf16 %0, %1, %2, %0" : "+v"(acc) : "v"(x.y), "v"(p.y));
    asm("v_dot2_f32_bf16 %0, %1, %2, %0" : "+v"(acc) : "v"(x.z), "v"(p.z));
    asm("v_dot2_f32_bf16 %0, %1, %2, %0" : "+v"(acc) : "v"(x.w), "v"(p.w));
    return acc;
}

// ---------------------------------------------------------------------------
// Prep: phiW[j][k] = bf16( alpha_j * w[k % CH] * phi_j[k] ),  j in [0,24)
// ---------------------------------------------------------------------------
__global__ void __launch_bounds__(256) prep_phi_kernel(
    const float* __restrict__ w,
    const float* __restrict__ phi_pre,
    const float* __restrict__ phi_post,
    const float* __restrict__ phi_res,
    const float* __restrict__ alpha_pre,
    const float* __restrict__ alpha_post,
    const float* __restrict__ alpha_res,
    uint16_t* __restrict__ phiW)
{
    int idx = blockIdx.x * 256 + threadIdx.x;
    if (idx >= NJ * NCF) return;
    int j = idx / NCF;
    int k = idx - j * NCF;
    int c = k & (CH - 1);
    float v, a;
    if (j < 4)      { v = phi_pre[j * NCF + k];        a = alpha_pre[0]; }
    else if (j < 8) { v = phi_post[(j - 4) * NCF + k]; a = alpha_post[0]; }
    else            { v = phi_res[(j - 8) * NCF + k];  a = alpha_res[0]; }
    phiW[idx] = (uint16_t)bf16rne(v * a * w[c]);
}

// ---------------------------------------------------------------------------
// Main fused kernel, WAVE-AUTONOMOUS. 512 threads (8 waves), TWO rows/block.
// No x in LDS: each wave sweeps the full x rows from cache (f32), computes
// its OWN sum-of-squares redundantly, converts to bf16 in-flight, dots
// against its 3 phi rows, folds scl at stream boundaries. ONE barrier.
// Sinkhorn redundant per wave; mix pass re-reads x f32 (exact) from cache.
// LDS ~1.4 KB; __launch_bounds__(512,4) pins VGPR <= 64 -> 4 blocks/CU.
// ---------------------------------------------------------------------------
__global__ void __launch_bounds__(512, 4) mhc_main_kernel(
    const float* __restrict__ x,
    const uint16_t* __restrict__ phiW,
    const float* __restrict__ b_pre,
    const float* __restrict__ b_post,
    const float* __restrict__ b_res,
    float* __restrict__ out)
{
    const int t = threadIdx.x;
    const int lane = t & 63;
    const int wave = t >> 6;              // 0..7
    const long b0 = (long)blockIdx.x * 2;

    __shared__ float hred[8][6];          // [wave][jl*2 + r]
    __shared__ float MS[2][16] __attribute__((aligned(16)));

    const float4* xp0 = reinterpret_cast<const float4*>(x + b0 * NCF);
    const float4* xp1 = reinterpret_cast<const float4*>(x + (b0 + 1) * NCF);
    const uint16_t* pw = phiW + (size_t)(wave * 3) * NCF;

    // ---- Phase B (fused with RMS): wave-autonomous sweep ----
    float accT[3][2] = {};
    #pragma unroll
    for (int s = 0; s < 4; ++s) {
        float accS[3][2] = {};
        float ss0 = 0.f, ss1 = 0.f;
        #pragma unroll
        for (int du = 0; du < 4; ++du) {
            const int q4 = 512 * s + 128 * du + 2 * lane;   // float4 index
            float4 a0 = xp0[q4], a0b = xp0[q4 + 1];
            float4 a1 = xp1[q4], a1b = xp1[q4 + 1];
            ss0 += a0.x*a0.x + a0.y*a0.y + a0.z*a0.z + a0.w*a0.w
                 + a0b.x*a0b.x + a0b.y*a0b.y + a0b.z*a0b.z + a0b.w*a0b.w;
            ss1 += a1.x*a1.x + a1.y*a1.y + a1.z*a1.z + a1.w*a1.w
                 + a1b.x*a1b.x + a1b.y*a1b.y + a1b.z*a1b.z + a1b.w*a1b.w;
            uint4 xq0 = make_uint4(cvtpk(a0.x, a0.y), cvtpk(a0.z, a0.w),
                                   cvtpk(a0b.x, a0b.y), cvtpk(a0b.z, a0b.w));
            uint4 xq1 = make_uint4(cvtpk(a1.x, a1.y), cvtpk(a1.z, a1.w),
                                   cvtpk(a1b.x, a1b.y), cvtpk(a1b.z, a1b.w));
            const int k = 4 * q4;                            // element index
            #pragma unroll
            for (int jl = 0; jl < 3; ++jl) {
                uint4 p = *reinterpret_cast<const uint4*>(pw + jl * NCF + k);
                accS[jl][0] = dot8(xq0, p, accS[jl][0]);
                accS[jl][1] = dot8(xq1, p, accS[jl][1]);
            }
        }
        // wave-local full-stream sum of squares -> scl (all lanes get it)
        #pragma unroll
        for (int m = 1; m < 64; m <<= 1) {
            ss0 += __shfl_xor(ss0, m, 64);
            ss1 += __shfl_xor(ss1, m, 64);
        }
        const float scl0 = rsqrtf(ss0 * (1.0f / CH) + EPS_F);
        const float scl1 = rsqrtf(ss1 * (1.0f / CH) + EPS_F);
        #pragma unroll
        for (int jl = 0; jl < 3; ++jl) {
            accT[jl][0] = fmaf(scl0, accS[jl][0], accT[jl][0]);
            accT[jl][1] = fmaf(scl1, accS[jl][1], accT[jl][1]);
        }
    }
    // reduce dot partials across the wave, fold bias, publish
    {
        #pragma unroll
        for (int m = 1; m < 64; m <<= 1) {
            #pragma unroll
            for (int jl = 0; jl < 3; ++jl) {
                accT[jl][0] += __shfl_xor(accT[jl][0], m, 64);
                accT[jl][1] += __shfl_xor(accT[jl][1], m, 64);
            }
        }
        if (lane == 0) {
            #pragma unroll
            for (int jl = 0; jl < 3; ++jl) {
                const int j = 3 * wave + jl;
                float bias;
                if (j < 4)      bias = b_pre[j];
                else if (j < 8) bias = b_post[j - 4];
                else            bias = b_res[j - 8];
                hred[wave][jl * 2 + 0] = accT[jl][0] + bias;
                hred[wave][jl * 2 + 1] = accT[jl][1] + bias;
            }
        }
    }
    __syncthreads();                      // the ONLY barrier

    // ---- Sinkhorn: redundant per wave; 16-lane group g does row g&1 ----
    {
        const int r = (lane >> 4) & 1;
        const int q = lane & 15;          // q = i*4 + jx
        const int j = 8 + q;
        float L = hred[j / 3][(j % 3) * 2 + r];
        float mx = L;
        mx = fmaxf(mx, __shfl_xor(mx, 1, 64));
        mx = fmaxf(mx, __shfl_xor(mx, 2, 64));
        mx = fmaxf(mx, __shfl_xor(mx, 4, 64));
        mx = fmaxf(mx, __shfl_xor(mx, 8, 64));
        float m = __expf(L - mx);
        #pragma unroll
        for (int it = 0; it < SINK_ITERS; ++it) {
            float rs = m + __shfl_xor(m, 1, 64);
            rs += __shfl_xor(rs, 2, 64);
            m = m * __builtin_amdgcn_rcpf(rs + EPS_F);   // row normalize
            float cs = m + __shfl_xor(m, 4, 64);
            cs += __shfl_xor(cs, 8, 64);
            m = m * __builtin_amdgcn_rcpf(cs + EPS_F);   // col normalize
        }
        MS[r][q] = m;                     // benign race; own-wave read below
    }

    // ---- Mix: re-read x f32 (cache-warm), exact f32, nt stores ----
    #pragma unroll
    for (int r = 0; r < 2; ++r) {
        float hp[4], hq[4];
        #pragma unroll
        for (int i = 0; i < 4; ++i) {
            hp[i] = hred[i / 3][(i % 3) * 2 + r] + b_pre[i];
            const int j = 4 + i;
            hq[i] = hred[j / 3][(j % 3) * 2 + r] + b_post[i];
        }
        float4 M[4];
        #pragma unroll
        for (int i = 0; i < 4; ++i) {
            float4 hrm = *reinterpret_cast<const float4*>(&MS[r][4 * i]);
            M[i].x = fmaf(hq[i], hp[0], hrm.x);
            M[i].y = fmaf(hq[i], hp[1], hrm.y);
            M[i].z = fmaf(hq[i], hp[2], hrm.z);
            M[i].w = fmaf(hq[i], hp[3], hrm.w);
        }
        const float4* xr = (r == 0) ? xp0 : xp1;
        float4 s0 = xr[t], s1 = xr[t + 512], s2 = xr[t + 1024], s3 = xr[t + 1536];
        v4f* op = reinterpret_cast<v4f*>(out + (b0 + r) * NCF) + t;
        #pragma unroll
        for (int i = 0; i < 4; ++i) {
            v4f o;
            o.x = M[i].x*s0.x + M[i].y*s1.x + M[i].z*s2.x + M[i].w*s3.x;
            o.y = M[i].x*s0.y + M[i].y*s1.y + M[i].z*s2.y + M[i].w*s3.y;
            o.z = M[i].x*s0.z + M[i].y*s1.z + M[i].z*s2.z + M[i].w*s3.z;
            o.w = M[i].x*s0.w + M[i].y*s1.w + M[i].z*s2.w + M[i].w*s3.w;
            __builtin_nontemporal_store(o, op + i * 512);
        }
    }
}

extern "C" void kernel_launch(void* const* d_in, const int* in_sizes, int n_in,
                              void* d_out, int out_size, void* d_ws, size_t ws_size,
                              hipStream_t stream)
{
    const float* x        = (const float*)d_in[0];
    const float* w        = (const float*)d_in[1];
    const float* phi_pre  = (const float*)d_in[2];
    const float* phi_post = (const float*)d_in[3];
    const float* phi_res  = (const float*)d_in[4];
    const float* b_pre    = (const float*)d_in[5];
    const float* b_post   = (const float*)d_in[6];
    const float* b_res    = (const float*)d_in[7];
    const float* a_pre    = (const float*)d_in[8];
    const float* a_post   = (const float*)d_in[9];
    const float* a_res    = (const float*)d_in[10];
    float* out = (float*)d_out;
    uint16_t* phiW = (uint16_t*)d_ws;   // NJ * NCF * 2 bytes = 384 KiB

    const int B = in_sizes[0] / NCF;    // 8192

    prep_phi_kernel<<<(NJ * NCF + 255) / 256, 256, 0, stream>>>(
        w, phi_pre, phi_post, phi_res, a_pre, a_post, a_res, phiW);

    mhc_main_kernel<<<B / 2, 512, 0, stream>>>(
        x, phiW, b_pre, b_post, b_res, out);
}

// Round 19
// 132.671 us; speedup vs baseline: 1.4896x; 1.4257x over previous
//
#include <hip/hip_runtime.h>
#include <hip/hip_bf16.h>
#include <cstdint>

#define CH 2048
#define NCF 8192          // 4 * CH
#define NJ 24             // 4 pre + 4 post + 16 res
#define RPB 4             // batch rows per block
#define EPS_F 1e-5f
#define SINK_ITERS 20

typedef float v4f __attribute__((ext_vector_type(4)));

__device__ __forceinline__ uint32_t bf16rne(float f) {
    uint32_t u = __float_as_uint(f);
    return (u + 0x7fffu + ((u >> 16) & 1u)) >> 16;
}

// pack 2 f32 -> 2 bf16 in one instruction (lo -> [15:0], hi -> [31:16])
__device__ __forceinline__ uint32_t cvtpk(float lo, float hi) {
    uint32_t r;
    asm("v_cvt_pk_bf16_f32 %0, %1, %2" : "=v"(r) : "v"(lo), "v"(hi));
    return r;
}

// dot of 8 bf16 pairs (packed in uint4) via v_dot2_f32_bf16
__device__ __forceinline__ float dot8(const uint4& x, const uint4& p, float acc) {
    asm("v_dot2_f32_bf16 %0, %1, %2, %0" : "+v"(acc) : "v"(x.x), "v"(p.x));
    asm("v_dot2_f32_bf16 %0, %1, %2, %0" : "+v"(acc) : "v"(x.y), "v"(p.y));
    asm("v_dot2_f32_bf16 %0, %1, %2, %0" : "+v"(acc) : "v"(x.z), "v"(p.z));
    asm("v_dot2_f32_bf16 %0, %1, %2, %0" : "+v"(acc) : "v"(x.w), "v"(p.w));
    return acc;
}

// ---------------------------------------------------------------------------
// Prep: phiW[j][k] = bf16( alpha_j * w[k % CH] * phi_j[k] ),  j in [0,24)
// ---------------------------------------------------------------------------
__global__ void __launch_bounds__(256) prep_phi_kernel(
    const float* __restrict__ w,
    const float* __restrict__ phi_pre,
    const float* __restrict__ phi_post,
    const float* __restrict__ phi_res,
    const float* __restrict__ alpha_pre,
    const float* __restrict__ alpha_post,
    const float* __restrict__ alpha_res,
    uint16_t* __restrict__ phiW)
{
    int idx = blockIdx.x * 256 + threadIdx.x;
    if (idx >= NJ * NCF) return;
    int j = idx / NCF;
    int k = idx - j * NCF;
    int c = k & (CH - 1);
    float v, a;
    if (j < 4)      { v = phi_pre[j * NCF + k];        a = alpha_pre[0]; }
    else if (j < 8) { v = phi_post[(j - 4) * NCF + k]; a = alpha_post[0]; }
    else            { v = phi_res[(j - 8) * NCF + k];  a = alpha_res[0]; }
    phiW[idx] = (uint16_t)bf16rne(v * a * w[c]);
}

// ---------------------------------------------------------------------------
// Main fused kernel: 512 threads (8 waves), FOUR batch rows per block.
// LDS holds raw bf16 x for 4 rows (64 KiB). RMS scale folded into the dot
// accumulation at stream-segment boundaries. Phase B: 2-step ping-pong phi
// prefetch with v_dot2_f32_bf16. Sinkhorn: all waves redundant, broadcast
// via MS LDS. 2 barriers total. (Champion configuration: 133 us.)
// ---------------------------------------------------------------------------
__global__ void __launch_bounds__(512) mhc_main_kernel(
    const float* __restrict__ x,
    const uint16_t* __restrict__ phiW,
    const float* __restrict__ b_pre,
    const float* __restrict__ b_post,
    const float* __restrict__ b_res,
    float* __restrict__ out)
{
    const int t = threadIdx.x;
    const int lane = t & 63;
    const int wave = t >> 6;              // 0..7
    const long b0 = (long)blockIdx.x * RPB;

    __shared__ uint32_t xn[RPB][NCF / 2]; // raw bf16 x, 4 rows, 64 KiB
    __shared__ float4 red[RPB][8];
    __shared__ float H[RPB][24] __attribute__((aligned(16)));
    __shared__ float MS[RPB][16] __attribute__((aligned(16)));

    // ---- Phase A: global -> LDS (raw bf16), sum-of-squares per stream ----
    // 2 rows batched: 8 float4 loads in flight before processing.
    {
        const float4* xp = reinterpret_cast<const float4*>(x + b0 * NCF);
        #pragma unroll
        for (int rp = 0; rp < RPB; rp += 2) {
            float4 a[2][4];
            #pragma unroll
            for (int rr = 0; rr < 2; ++rr)
                #pragma unroll
                for (int jj = 0; jj < 4; ++jj)
                    a[rr][jj] = xp[(rp + rr) * 2048 + t + 512 * jj];

            float ss[2][4];
            #pragma unroll
            for (int rr = 0; rr < 2; ++rr) {
                const int r = rp + rr;
                #pragma unroll
                for (int jj = 0; jj < 4; ++jj) {
                    float4 v = a[rr][jj];
                    ss[rr][jj] = v.x*v.x + v.y*v.y + v.z*v.z + v.w*v.w;
                    *reinterpret_cast<uint2*>(&xn[r][2*t + 1024*jj]) =
                        make_uint2(cvtpk(v.x, v.y), cvtpk(v.z, v.w));
                }
            }
            #pragma unroll
            for (int m = 1; m < 64; m <<= 1) {
                #pragma unroll
                for (int rr = 0; rr < 2; ++rr)
                    #pragma unroll
                    for (int jj = 0; jj < 4; ++jj)
                        ss[rr][jj] += __shfl_xor(ss[rr][jj], m, 64);
            }
            if (lane == 0) {
                red[rp][wave]     = make_float4(ss[0][0], ss[0][1], ss[0][2], ss[0][3]);
                red[rp + 1][wave] = make_float4(ss[1][0], ss[1][1], ss[1][2], ss[1][3]);
            }
        }
    }
    __syncthreads();

    // ---- SCL computed redundantly per thread (broadcast LDS reads) ----
    float scl[RPB][4];
    #pragma unroll
    for (int r = 0; r < RPB; ++r) {
        float sx = 0.f, sy = 0.f, sz = 0.f, sw = 0.f;
        #pragma unroll
        for (int w8 = 0; w8 < 8; ++w8) {
            float4 v = red[r][w8];
            sx += v.x; sy += v.y; sz += v.z; sw += v.w;
        }
        scl[r][0] = rsqrtf(sx * (1.0f / CH) + EPS_F);
        scl[r][1] = rsqrtf(sy * (1.0f / CH) + EPS_F);
        scl[r][2] = rsqrtf(sz * (1.0f / CH) + EPS_F);
        scl[r][3] = rsqrtf(sw * (1.0f / CH) + EPS_F);
    }

    // ---- Phase B: wave w dots 4 raw rows against phi rows 3w..3w+2 ----
    // 16 steps of 512 elems; 2-step ping-pong; scl folded per stream segment.
    float accT[3][RPB] = {};
    float accS[3][RPB] = {};
    {
        const uint16_t* pw = phiW + (size_t)(wave * 3) * NCF;
        const int kl = 8 * lane;
        const uint4* xr0 = reinterpret_cast<const uint4*>(xn[0]);
        const uint4* xr1 = reinterpret_cast<const uint4*>(xn[1]);
        const uint4* xr2 = reinterpret_cast<const uint4*>(xn[2]);
        const uint4* xr3 = reinterpret_cast<const uint4*>(xn[3]);

        uint4 pA0 = *reinterpret_cast<const uint4*>(pw + 0 * NCF + kl);
        uint4 pA1 = *reinterpret_cast<const uint4*>(pw + 1 * NCF + kl);
        uint4 pA2 = *reinterpret_cast<const uint4*>(pw + 2 * NCF + kl);
        uint4 xA0 = xr0[lane], xA1 = xr1[lane], xA2 = xr2[lane], xA3 = xr3[lane];

        #pragma unroll
        for (int u = 0; u < 16; u += 2) {
            const int iB = 64 * (u + 1) + lane;
            const int kB = 512 * (u + 1) + kl;
            uint4 pB0 = *reinterpret_cast<const uint4*>(pw + 0 * NCF + kB);
            uint4 pB1 = *reinterpret_cast<const uint4*>(pw + 1 * NCF + kB);
            uint4 pB2 = *reinterpret_cast<const uint4*>(pw + 2 * NCF + kB);
            uint4 xB0 = xr0[iB], xB1 = xr1[iB], xB2 = xr2[iB], xB3 = xr3[iB];

            accS[0][0] = dot8(xA0, pA0, accS[0][0]);
            accS[0][1] = dot8(xA1, pA0, accS[0][1]);
            accS[0][2] = dot8(xA2, pA0, accS[0][2]);
            accS[0][3] = dot8(xA3, pA0, accS[0][3]);
            accS[1][0] = dot8(xA0, pA1, accS[1][0]);
            accS[1][1] = dot8(xA1, pA1, accS[1][1]);
            accS[1][2] = dot8(xA2, pA1, accS[1][2]);
            accS[1][3] = dot8(xA3, pA1, accS[1][3]);
            accS[2][0] = dot8(xA0, pA2, accS[2][0]);
            accS[2][1] = dot8(xA1, pA2, accS[2][1]);
            accS[2][2] = dot8(xA2, pA2, accS[2][2]);
            accS[2][3] = dot8(xA3, pA2, accS[2][3]);

            if (u + 2 < 16) {
                const int iA = 64 * (u + 2) + lane;
                const int kA = 512 * (u + 2) + kl;
                pA0 = *reinterpret_cast<const uint4*>(pw + 0 * NCF + kA);
                pA1 = *reinterpret_cast<const uint4*>(pw + 1 * NCF + kA);
                pA2 = *reinterpret_cast<const uint4*>(pw + 2 * NCF + kA);
                xA0 = xr0[iA]; xA1 = xr1[iA]; xA2 = xr2[iA]; xA3 = xr3[iA];
            }

            accS[0][0] = dot8(xB0, pB0, accS[0][0]);
            accS[0][1] = dot8(xB1, pB0, accS[0][1]);
            accS[0][2] = dot8(xB2, pB0, accS[0][2]);
            accS[0][3] = dot8(xB3, pB0, accS[0][3]);
            accS[1][0] = dot8(xB0, pB1, accS[1][0]);
            accS[1][1] = dot8(xB1, pB1, accS[1][1]);
            accS[1][2] = dot8(xB2, pB1, accS[1][2]);
            accS[1][3] = dot8(xB3, pB1, accS[1][3]);
            accS[2][0] = dot8(xB0, pB2, accS[2][0]);
            accS[2][1] = dot8(xB1, pB2, accS[2][1]);
            accS[2][2] = dot8(xB2, pB2, accS[2][2]);
            accS[2][3] = dot8(xB3, pB2, accS[2][3]);

            if (((u + 1) & 3) == 3) {               // end of stream segment
                const int s = (u + 1) >> 2;
                #pragma unroll
                for (int jl = 0; jl < 3; ++jl) {
                    #pragma unroll
                    for (int r = 0; r < RPB; ++r) {
                        accT[jl][r] = fmaf(scl[r][s], accS[jl][r], accT[jl][r]);
                        accS[jl][r] = 0.f;
                    }
                }
            }
        }
    }
    {
        #pragma unroll
        for (int m = 1; m < 64; m <<= 1) {
            #pragma unroll
            for (int jl = 0; jl < 3; ++jl) {
                #pragma unroll
                for (int r = 0; r < RPB; ++r)
                    accT[jl][r] += __shfl_xor(accT[jl][r], m, 64);
            }
        }
        if (lane == 0) {                 // fold bias, write H directly
            #pragma unroll
            for (int jl = 0; jl < 3; ++jl) {
                int j = 3 * wave + jl;
                float bias;
                if (j < 4)      bias = b_pre[j];
                else if (j < 8) bias = b_post[j - 4];
                else            bias = b_res[j - 8];
                #pragma unroll
                for (int r = 0; r < RPB; ++r) H[r][j] = accT[jl][r] + bias;
            }
        }
    }
    __syncthreads();

    // ---- Sinkhorn: every wave computes all 4 rows redundantly (16-lane
    // groups); identical-value writes to MS (benign race, own-wave read).
    {
        const int r = lane >> 4;
        const int q = lane & 15;          // q = i*4 + jx
        float L = H[r][8 + q];
        float mx = L;
        mx = fmaxf(mx, __shfl_xor(mx, 1, 64));
        mx = fmaxf(mx, __shfl_xor(mx, 2, 64));
        mx = fmaxf(mx, __shfl_xor(mx, 4, 64));
        mx = fmaxf(mx, __shfl_xor(mx, 8, 64));
        float m = __expf(L - mx);
        #pragma unroll
        for (int it = 0; it < SINK_ITERS; ++it) {
            float rs = m + __shfl_xor(m, 1, 64);
            rs += __shfl_xor(rs, 2, 64);
            m = m * __builtin_amdgcn_rcpf(rs + EPS_F);   // row normalize
            float cs = m + __shfl_xor(m, 4, 64);
            cs += __shfl_xor(cs, 8, 64);
            m = m * __builtin_amdgcn_rcpf(cs + EPS_F);   // col normalize
        }
        MS[r][q] = m;
    }

    // ---- Phase D: mixing epilogue from LDS raw bf16 x; h via LDS float4 --
    #pragma unroll
    for (int r = 0; r < RPB; ++r) {
        const float4 hp = *reinterpret_cast<const float4*>(&H[r][0]);
        const float4 hq = *reinterpret_cast<const float4*>(&H[r][4]);
        float4 hrm[4];
        #pragma unroll
        for (int i = 0; i < 4; ++i)
            hrm[i] = *reinterpret_cast<const float4*>(&MS[r][4 * i]);
        float4 s[4];
        #pragma unroll
        for (int jj = 0; jj < 4; ++jj) {
            uint2 pk = *reinterpret_cast<const uint2*>(&xn[r][2 * t + 1024 * jj]);
            s[jj].x = __uint_as_float(pk.x << 16);
            s[jj].y = __uint_as_float(pk.x & 0xffff0000u);
            s[jj].z = __uint_as_float(pk.y << 16);
            s[jj].w = __uint_as_float(pk.y & 0xffff0000u);
        }
        float ax = hp.x*s[0].x + hp.y*s[1].x + hp.z*s[2].x + hp.w*s[3].x;
        float ay = hp.x*s[0].y + hp.y*s[1].y + hp.z*s[2].y + hp.w*s[3].y;
        float az = hp.x*s[0].z + hp.y*s[1].z + hp.z*s[2].z + hp.w*s[3].z;
        float aw = hp.x*s[0].w + hp.y*s[1].w + hp.z*s[2].w + hp.w*s[3].w;
        const float hqv[4] = {hq.x, hq.y, hq.z, hq.w};
        v4f* op = reinterpret_cast<v4f*>(out + (b0 + r) * NCF + 4 * t);
        #pragma unroll
        for (int i = 0; i < 4; ++i) {
            v4f o;
            o.x = hrm[i].x*s[0].x + hrm[i].y*s[1].x + hrm[i].z*s[2].x + hrm[i].w*s[3].x + hqv[i]*ax;
            o.y = hrm[i].x*s[0].y + hrm[i].y*s[1].y + hrm[i].z*s[2].y + hrm[i].w*s[3].y + hqv[i]*ay;
            o.z = hrm[i].x*s[0].z + hrm[i].y*s[1].z + hrm[i].z*s[2].z + hrm[i].w*s[3].z + hqv[i]*az;
            o.w = hrm[i].x*s[0].w + hrm[i].y*s[1].w + hrm[i].z*s[2].w + hrm[i].w*s[3].w + hqv[i]*aw;
            __builtin_nontemporal_store(o, op + i * 512);
        }
    }
}

extern "C" void kernel_launch(void* const* d_in, const int* in_sizes, int n_in,
                              void* d_out, int out_size, void* d_ws, size_t ws_size,
                              hipStream_t stream)
{
    const float* x        = (const float*)d_in[0];
    const float* w        = (const float*)d_in[1];
    const float* phi_pre  = (const float*)d_in[2];
    const float* phi_post = (const float*)d_in[3];
    const float* phi_res  = (const float*)d_in[4];
    const float* b_pre    = (const float*)d_in[5];
    const float* b_post   = (const float*)d_in[6];
    const float* b_res    = (const float*)d_in[7];
    const float* a_pre    = (const float*)d_in[8];
    const float* a_post   = (const float*)d_in[9];
    const float* a_res    = (const float*)d_in[10];
    float* out = (float*)d_out;
    uint16_t* phiW = (uint16_t*)d_ws;   // NJ * NCF * 2 bytes = 384 KiB

    const int B = in_sizes[0] / NCF;    // 8192

    prep_phi_kernel<<<(NJ * NCF + 255) / 256, 256, 0, stream>>>(
        w, phi_pre, phi_post, phi_res, a_pre, a_post, a_res, phiW);

    mhc_main_kernel<<<B / RPB, 512, 0, stream>>>(
        x, phiW, b_pre, b_post, b_res, out);
}